// Round 10
// baseline (137.343 us; speedup 1.0000x reference)
//
#include <hip/hip_runtime.h>
#include <math.h>

#define NP 8      // paths
#define ND 128    // D = c / P
#define NC 1024   // channels = NP*ND
#define NL 4096   // sequence length
#define NB 16     // batch
#define LN_EPS 1e-5f

#define NBLK 2048           // 8 blocks/CU x 256 CUs (full co-residency)
#define NCHUNK 4            // 4 batches (64 MB) per chunk -> L3-resident re-read
#define RPC 2               // rows per block per chunk (consecutive, same batch)
#define GRPS 64             // barrier groups (32 blocks each)

typedef float v4f __attribute__((ext_vector_type(4)));

__device__ __forceinline__ float hsum(v4f v) { return v.x + v.y + v.z + v.w; }
__device__ __forceinline__ float sigmoid_f(float z) { return 1.f / (1.f + expf(-z)); }

// expf-only tanh-GELU (no erff libcall). |err| ~1e-3 << 2.8e-2 threshold.
__device__ __forceinline__ float gelu_f(float s) {
    const float t = 0.7978845608028654f * (s + 0.044715f * s * s * s);
    const float e = expf(2.f * t);
    return 0.5f * s * (1.f + (e - 1.f) / (e + 1.f));
}

// ================= Persistent fused kernel: L3-resident chunk re-read ========
// Per chunk c (4 batches, 64 MB): block owns rows r0=c*8192+2*bid, r0+1 (same
// batch). Phase A: read rows (allocate L3), reduce -> y. Barrier. Phase B:
// redundant attn+gate from y. Phase C: RE-READ rows (L3 hit, 64MB << 256MB),
// scale, nontemporal store. No state crosses the barrier -> nothing to spill.
__global__ __launch_bounds__(256, 8) void fused_kernel(
    const float* __restrict__ x, float* __restrict__ y,
    unsigned* __restrict__ garr, unsigned* __restrict__ grel,
    unsigned* __restrict__ root,
    const float* __restrict__ conv1_w, const float* __restrict__ conv2_w,
    const float* __restrict__ combine_w, const float* __restrict__ combine_b,
    const float* __restrict__ ln_g, const float* __restrict__ ln_b,
    const float* __restrict__ W1, const float* __restrict__ b1,
    const float* __restrict__ W2, const float* __restrict__ b2,
    float* __restrict__ out)
{
    const int tid    = threadIdx.x;
    const int bid    = blockIdx.x;
    const int grp    = bid >> 5;             // 32 blocks per group
    const bool lead  = (bid & 31) == 0;

    __shared__ float sred[RPC][4];
    __shared__ float sy[NC];
    __shared__ float sattn[NC];
    __shared__ float scross[NP];
    __shared__ float sh[NP];
    __shared__ float sh2[2 * NP];
    __shared__ float sgate[NP];
    __shared__ float sml[2];                 // mu, inv

    for (int c = 0; c < NCHUNK; ++c) {
        const int r0  = c * (NBLK * RPC) + RPC * bid;   // rows r0, r0+1 (same batch)
        const int b   = r0 >> 10;
        const int ch0 = r0 & (NC - 1);
        const v4f* x0 = (const v4f*)x + (size_t)r0 * (NL / 4);
        v4f* o0       = (v4f*)out    + (size_t)r0 * (NL / 4);

        // ---- Phase A: read rows (allocate in L3), reduce -> y ----
        #pragma unroll
        for (int r = 0; r < RPC; ++r) {
            const v4f* xr = x0 + (size_t)r * (NL / 4);
            float ps = hsum(xr[tid]) + hsum(xr[tid + 256])
                     + hsum(xr[tid + 512]) + hsum(xr[tid + 768]);
            ps += __shfl_down(ps, 32, 64); ps += __shfl_down(ps, 16, 64);
            ps += __shfl_down(ps, 8, 64);  ps += __shfl_down(ps, 4, 64);
            ps += __shfl_down(ps, 2, 64);  ps += __shfl_down(ps, 1, 64);
            if ((tid & 63) == 0) sred[r][tid >> 6] = ps;
        }
        __syncthreads();
        if (tid == 0) {
            #pragma unroll
            for (int r = 0; r < RPC; ++r) {
                const float ym = (sred[r][0] + sred[r][1] + sred[r][2] + sred[r][3]) * (1.f / NL);
                __hip_atomic_store(&y[r0 + r], ym, __ATOMIC_RELAXED, __HIP_MEMORY_SCOPE_AGENT);
            }
            // arrive (release orders the y stores before the count)
            unsigned old = __hip_atomic_fetch_add(&garr[grp], 1u,
                              __ATOMIC_RELEASE, __HIP_MEMORY_SCOPE_AGENT);
            if (old == (unsigned)(c * 32 + 31))
                __hip_atomic_fetch_add(root, 1u,
                              __ATOMIC_RELEASE, __HIP_MEMORY_SCOPE_AGENT);
            // two-level wait: leaders on root, followers on per-group line
            if (lead) {
                while (__hip_atomic_load(root, __ATOMIC_RELAXED,
                                         __HIP_MEMORY_SCOPE_AGENT) < (unsigned)((c + 1) * GRPS))
                    __builtin_amdgcn_s_sleep(4);
                __hip_atomic_store(&grel[grp], (unsigned)(c + 1),
                                   __ATOMIC_RELAXED, __HIP_MEMORY_SCOPE_AGENT);
            } else {
                while (__hip_atomic_load(&grel[grp], __ATOMIC_RELAXED,
                                         __HIP_MEMORY_SCOPE_AGENT) < (unsigned)(c + 1))
                    __builtin_amdgcn_s_sleep(4);
            }
        }
        __syncthreads();

        // ---- Phase B: attn + gate for this block's batch (redundant) ----
        const float* yb = y + b * NC;
        #pragma unroll
        for (int k = 0; k < 4; ++k) {
            const int i = tid + 256 * k;    // agent-scope: dodge stale XCD-L2 lines
            sy[i] = __hip_atomic_load(&yb[i], __ATOMIC_RELAXED, __HIP_MEMORY_SCOPE_AGENT);
        }
        __syncthreads();
        #pragma unroll
        for (int k = 0; k < 4; ++k) {
            const int pos = tid + 256 * k;
            const int p = pos >> 7, d = pos & 127;
            const float* rowp = sy + p * ND;
            float c1 = 0.f;
            #pragma unroll
            for (int t = 0; t < 5; ++t) {
                int dd = d + t - 2;
                float v = (dd >= 0 && dd < ND) ? rowp[dd] : 0.f;
                c1 += conv1_w[p * 5 + t] * v;
            }
            float c2 = 0.f;
            #pragma unroll
            for (int t = 0; t < 9; ++t) {
                int dd = d + t - 4;
                float v = (dd >= 0 && dd < ND) ? rowp[dd] : 0.f;
                c2 += conv2_w[p * 9 + t] * v;
            }
            sattn[pos] = sigmoid_f(combine_w[0] * c1 + combine_w[1] * c2 + combine_b[0]);
        }
        __syncthreads();
        if (tid < 128) {                    // per-path means: 16 lanes/path, 8 elems each
            const int p = tid >> 4, o = (tid & 15) * 8;
            float s = 0.f;
            #pragma unroll
            for (int j = 0; j < 8; ++j) s += sattn[p * ND + o + j];
            s += __shfl_down(s, 8, 16); s += __shfl_down(s, 4, 16);
            s += __shfl_down(s, 2, 16); s += __shfl_down(s, 1, 16);
            if ((tid & 15) == 0) scross[p] = s * (1.f / ND);
        }
        __syncthreads();
        if (tid == 0) {
            float mu = 0.f;
            #pragma unroll
            for (int pp = 0; pp < NP; ++pp) mu += scross[pp];
            mu *= (1.f / NP);
            float var = 0.f;
            #pragma unroll
            for (int pp = 0; pp < NP; ++pp) { float dl = scross[pp] - mu; var += dl * dl; }
            sml[0] = mu;
            sml[1] = rsqrtf(var * (1.f / NP) + LN_EPS);
        }
        __syncthreads();
        if (tid < NP)
            sh[tid] = (scross[tid] - sml[0]) * sml[1] * ln_g[tid] + ln_b[tid];
        __syncthreads();
        if (tid < 2 * NP) {
            float s = b1[tid];
            #pragma unroll
            for (int pp = 0; pp < NP; ++pp) s += sh[pp] * W1[pp * (2 * NP) + tid];
            sh2[tid] = gelu_f(s);
        }
        __syncthreads();
        if (tid < NP) {
            float s = b2[tid];
            #pragma unroll
            for (int j = 0; j < 2 * NP; ++j) s += sh2[j] * W2[j * NP + tid];
            sgate[tid] = sigmoid_f(s);
        }
        __syncthreads();

        // ---- Phase C: re-read rows (L3 hit), scale, nt-store ----
        #pragma unroll
        for (int r = 0; r < RPC; ++r) {
            const float s = sattn[ch0 + r] * sgate[(ch0 + r) >> 7];
            const v4f* xr = x0 + (size_t)r * (NL / 4);
            v4f* orr      = o0 + (size_t)r * (NL / 4);
            __builtin_nontemporal_store(xr[tid]       * s, &orr[tid]);
            __builtin_nontemporal_store(xr[tid + 256] * s, &orr[tid + 256]);
            __builtin_nontemporal_store(xr[tid + 512] * s, &orr[tid + 512]);
            __builtin_nontemporal_store(xr[tid + 768] * s, &orr[tid + 768]);
        }
        __syncthreads();                    // protect LDS before next chunk reuses it
    }
}

// ================= Fallback path (R4 kernels, 133 us) =================
__global__ __launch_bounds__(256) void pool_kernel(const float* __restrict__ x,
                                                   float* __restrict__ y) {
    const int wid  = threadIdx.x >> 6;
    const int lane = threadIdx.x & 63;
    const int row  = blockIdx.x * 4 + wid;
    const v4f* xr = (const v4f*)(x + (size_t)row * NL);
    float s = 0.f;
    #pragma unroll
    for (int i = 0; i < 16; ++i) {
        v4f v = xr[lane + i * 64];
        s += v.x + v.y + v.z + v.w;
    }
    #pragma unroll
    for (int off = 32; off; off >>= 1) s += __shfl_down(s, off, 64);
    if (lane == 0) y[row] = s * (1.f / NL);
}

__global__ __launch_bounds__(1024) void attn_kernel(
    const float* __restrict__ y,
    const float* __restrict__ conv1_w, const float* __restrict__ conv2_w,
    const float* __restrict__ combine_w, const float* __restrict__ combine_b,
    const float* __restrict__ ln_g, const float* __restrict__ ln_b,
    const float* __restrict__ W1, const float* __restrict__ b1,
    const float* __restrict__ W2, const float* __restrict__ b2,
    float* __restrict__ scale)
{
    const int b = blockIdx.x;
    const int tid = threadIdx.x;
    const int p = tid >> 7;
    const int d = tid & 127;

    __shared__ float sy[NC];
    __shared__ float sattn[NC];
    __shared__ float sred[16];
    __shared__ float scross[NP];
    __shared__ float sh[NP];
    __shared__ float sh2[2 * NP];
    __shared__ float sgate[NP];
    __shared__ float sml[2];

    sy[tid] = y[b * NC + tid];
    __syncthreads();

    const float* rowp = sy + p * ND;
    float c1 = 0.f;
    #pragma unroll
    for (int t = 0; t < 5; ++t) {
        int dd = d + t - 2;
        float v = (dd >= 0 && dd < ND) ? rowp[dd] : 0.f;
        c1 += conv1_w[p * 5 + t] * v;
    }
    float c2 = 0.f;
    #pragma unroll
    for (int t = 0; t < 9; ++t) {
        int dd = d + t - 4;
        float v = (dd >= 0 && dd < ND) ? rowp[dd] : 0.f;
        c2 += conv2_w[p * 9 + t] * v;
    }
    const float a = sigmoid_f(combine_w[0] * c1 + combine_w[1] * c2 + combine_b[0]);
    sattn[tid] = a;

    float r = a;
    #pragma unroll
    for (int off = 32; off; off >>= 1) r += __shfl_down(r, off, 64);
    const int lane = tid & 63, wid = tid >> 6;
    if (lane == 0) sred[wid] = r;
    __syncthreads();

    if (tid == 0) {
        float mu = 0.f, var = 0.f;
        #pragma unroll
        for (int pp = 0; pp < NP; ++pp) {
            scross[pp] = (sred[2 * pp] + sred[2 * pp + 1]) * (1.f / ND);
            mu += scross[pp];
        }
        mu *= (1.f / NP);
        #pragma unroll
        for (int pp = 0; pp < NP; ++pp) { float dl = scross[pp] - mu; var += dl * dl; }
        sml[0] = mu;
        sml[1] = rsqrtf(var * (1.f / NP) + LN_EPS);
    }
    __syncthreads();
    if (tid < NP)
        sh[tid] = (scross[tid] - sml[0]) * sml[1] * ln_g[tid] + ln_b[tid];
    __syncthreads();
    if (tid < 2 * NP) {
        float s = b1[tid];
        #pragma unroll
        for (int pp = 0; pp < NP; ++pp) s += sh[pp] * W1[pp * (2 * NP) + tid];
        sh2[tid] = gelu_f(s);
    }
    __syncthreads();
    if (tid < NP) {
        float s = b2[tid];
        #pragma unroll
        for (int j = 0; j < 2 * NP; ++j) s += sh2[j] * W2[j * NP + tid];
        sgate[tid] = sigmoid_f(s);
    }
    __syncthreads();

    scale[b * NC + tid] = sattn[tid] * sgate[p];
}

__global__ __launch_bounds__(256) void scale_kernel(const float* __restrict__ x,
                                                    const float* __restrict__ scale,
                                                    float* __restrict__ out) {
    const v4f* xv = (const v4f*)x;
    v4f* ov = (v4f*)out;
    const size_t n = (size_t)NB * NC * (NL / 4);
    const size_t stride = (size_t)gridDim.x * blockDim.x;
    for (size_t i = (size_t)blockIdx.x * blockDim.x + threadIdx.x; i < n; i += stride) {
        const float s = scale[i >> 10];
        v4f v = xv[i];
        v *= s;
        __builtin_nontemporal_store(v, &ov[i]);
    }
}

extern "C" void kernel_launch(void* const* d_in, const int* in_sizes, int n_in,
                              void* d_out, int out_size, void* d_ws, size_t ws_size,
                              hipStream_t stream) {
    const float* x         = (const float*)d_in[0];
    const float* conv1_w   = (const float*)d_in[1];
    const float* conv2_w   = (const float*)d_in[2];
    const float* combine_w = (const float*)d_in[3];
    const float* combine_b = (const float*)d_in[4];
    const float* ln_g      = (const float*)d_in[5];
    const float* ln_b      = (const float*)d_in[6];
    const float* W1        = (const float*)d_in[7];
    const float* b1        = (const float*)d_in[8];
    const float* W2        = (const float*)d_in[9];
    const float* b2        = (const float*)d_in[10];
    float* out = (float*)d_out;

    float* y        = (float*)d_ws;                    // [0,64KB): pooled means
    float* scale    = y + NB * NC;                     // [64KB,128KB): fallback only
    unsigned* garr  = (unsigned*)(void*)scale;         // coop: overlaps scale region
    unsigned* grel  = garr + GRPS;
    unsigned* root  = grel + GRPS;

    // zero barrier counters each launch (graph-capturable, deterministic)
    hipMemsetAsync((void*)garr, 0, (2 * GRPS + 16) * sizeof(unsigned), stream);

    int nb = 0;
    hipOccupancyMaxActiveBlocksPerMultiprocessor(&nb, fused_kernel, 256, 0);
    if (nb >= NBLK / 256) {
        void* args[] = { (void*)&x, (void*)&y, (void*)&garr, (void*)&grel, (void*)&root,
                         (void*)&conv1_w, (void*)&conv2_w,
                         (void*)&combine_w, (void*)&combine_b,
                         (void*)&ln_g, (void*)&ln_b,
                         (void*)&W1, (void*)&b1, (void*)&W2, (void*)&b2,
                         (void*)&out };
        hipLaunchCooperativeKernel((const void*)fused_kernel, dim3(NBLK), dim3(256),
                                   args, 0, stream);
    } else {
        pool_kernel<<<NB * NC / 4, 256, 0, stream>>>(x, y);
        attn_kernel<<<NB, 1024, 0, stream>>>(y, conv1_w, conv2_w, combine_w, combine_b,
                                             ln_g, ln_b, W1, b1, W2, b2, scale);
        scale_kernel<<<2048, 256, 0, stream>>>(x, scale, out);
    }
}

// Round 11
// 137.261 us; speedup vs baseline: 1.0006x; 1.0006x over previous
//
#include <hip/hip_runtime.h>
#include <math.h>

#define NP 8      // paths
#define ND 128    // D = c / P
#define NC 1024   // channels = NP*ND
#define NL 4096   // sequence length
#define NB 16     // batch
#define LN_EPS 1e-5f

#define NBLK 1024           // 4 blocks/CU x 256 CUs (co-resident; LDS-capped)
#define NT   512
#define RPC  2              // rows per block per chunk
#define NCHUNK 8            // 1024*2*8 = 16384 rows
#define GRPS 32             // barrier groups (32 blocks each)

typedef float v4f __attribute__((ext_vector_type(4)));

__device__ __forceinline__ float hsum(v4f v) { return v.x + v.y + v.z + v.w; }
__device__ __forceinline__ float sigmoid_f(float z) { return 1.f / (1.f + expf(-z)); }

// expf-only tanh-GELU (no erff libcall). |err| ~1e-3 << 2.8e-2 threshold.
__device__ __forceinline__ float gelu_f(float s) {
    const float t = 0.7978845608028654f * (s + 0.044715f * s * s * s);
    const float e = expf(2.f * t);
    return 0.5f * s * (1.f + (e - 1.f) / (e + 1.f));
}

// ============ Persistent fused kernel: x staged in LDS across barrier ========
// Per chunk c: block owns rows r0=c*2048+2*bid, r0+1 (same batch, same path).
// A: read rows from HBM ONCE -> LDS srow (thread-private slots) + reduce -> y.
//    grid barrier (tid0 only; no VGPR payload crosses the spin).
// B: redundant per-block attn over own batch (from y) + LN/MLP/gate.
// C: read srow from LDS, scale, nontemporal store. HBM total = 512 MB.
__global__ __launch_bounds__(NT, 8) void fused_kernel(
    const float* __restrict__ x, float* __restrict__ y,
    unsigned* __restrict__ garr, unsigned* __restrict__ grel,
    unsigned* __restrict__ root,
    const float* __restrict__ conv1_w, const float* __restrict__ conv2_w,
    const float* __restrict__ combine_w, const float* __restrict__ combine_b,
    const float* __restrict__ ln_g, const float* __restrict__ ln_b,
    const float* __restrict__ W1, const float* __restrict__ b1,
    const float* __restrict__ W2, const float* __restrict__ b2,
    float* __restrict__ out)
{
    const int tid  = threadIdx.x;
    const int bid  = blockIdx.x;
    const int grp  = bid >> 5;
    const bool lead = (bid & 31) == 0;
    const int r    = tid >> 8;          // 0/1: which of the block's 2 rows
    const int col  = tid & 255;         // v4f column base within the row

    __shared__ v4f   srow[RPC][NL / 4];     // 32 KB: the staged x rows
    __shared__ float sy[NC];                // 4 KB: own batch's pooled means
    __shared__ float sred[RPC][4];
    __shared__ float scross[NP];
    __shared__ float sh[NP];
    __shared__ float sh2[2 * NP];
    __shared__ float sgate[NP];
    __shared__ float sml[2];
    __shared__ float sscale[RPC];

    for (int c = 0; c < NCHUNK; ++c) {
        const int r0  = c * (NBLK * RPC) + RPC * bid;
        const int b   = r0 >> 10;
        const int ch0 = r0 & (NC - 1);       // even; ch0,ch0+1 same path

        // ---- Phase A: HBM -> LDS + pool ----
        {
            const v4f* xr = (const v4f*)x + (size_t)(r0 + r) * (NL / 4);
            v4f v0 = xr[col], v1 = xr[col + 256], v2 = xr[col + 512], v3 = xr[col + 768];
            srow[r][col]       = v0;
            srow[r][col + 256] = v1;
            srow[r][col + 512] = v2;
            srow[r][col + 768] = v3;
            float ps = hsum(v0) + hsum(v1) + hsum(v2) + hsum(v3);
            ps += __shfl_down(ps, 32, 64); ps += __shfl_down(ps, 16, 64);
            ps += __shfl_down(ps, 8, 64);  ps += __shfl_down(ps, 4, 64);
            ps += __shfl_down(ps, 2, 64);  ps += __shfl_down(ps, 1, 64);
            if ((tid & 63) == 0) sred[r][(tid >> 6) & 3] = ps;
        }
        __syncthreads();
        if (tid == 0) {
            #pragma unroll
            for (int rr = 0; rr < RPC; ++rr) {
                const float ym = (sred[rr][0] + sred[rr][1] + sred[rr][2] + sred[rr][3]) * (1.f / NL);
                __hip_atomic_store(&y[r0 + rr], ym, __ATOMIC_RELAXED, __HIP_MEMORY_SCOPE_AGENT);
            }
            // arrive (release orders y stores before count)
            unsigned old = __hip_atomic_fetch_add(&garr[grp], 1u,
                              __ATOMIC_RELEASE, __HIP_MEMORY_SCOPE_AGENT);
            if (old == (unsigned)(c * 32 + 31))
                __hip_atomic_fetch_add(root, 1u,
                              __ATOMIC_RELEASE, __HIP_MEMORY_SCOPE_AGENT);
            // two-level wait: leaders on root, followers on per-group line
            if (lead) {
                while (__hip_atomic_load(root, __ATOMIC_RELAXED,
                                         __HIP_MEMORY_SCOPE_AGENT) < (unsigned)((c + 1) * GRPS))
                    __builtin_amdgcn_s_sleep(4);
                __hip_atomic_store(&grel[grp], (unsigned)(c + 1),
                                   __ATOMIC_RELAXED, __HIP_MEMORY_SCOPE_AGENT);
            } else {
                while (__hip_atomic_load(&grel[grp], __ATOMIC_RELAXED,
                                         __HIP_MEMORY_SCOPE_AGENT) < (unsigned)(c + 1))
                    __builtin_amdgcn_s_sleep(4);
            }
        }
        __syncthreads();

        // ---- Phase B: attn + gate for own batch (redundant per block) ----
        {
            const float* yb = y + b * NC;   // agent-scope: dodge stale XCD-L2 lines
            sy[tid]       = __hip_atomic_load(&yb[tid],       __ATOMIC_RELAXED, __HIP_MEMORY_SCOPE_AGENT);
            sy[tid + 512] = __hip_atomic_load(&yb[tid + 512], __ATOMIC_RELAXED, __HIP_MEMORY_SCOPE_AGENT);
        }
        __syncthreads();
        float aa0, aa1;                     // attn at positions 2*tid, 2*tid+1
        {
            #pragma unroll
            for (int k = 0; k < 2; ++k) {
                const int pos = 2 * tid + k;
                const int p = pos >> 7, d = pos & 127;
                const float* rowp = sy + p * ND;
                float c1 = 0.f;
                #pragma unroll
                for (int t = 0; t < 5; ++t) {
                    int dd = d + t - 2;
                    float v = (dd >= 0 && dd < ND) ? rowp[dd] : 0.f;
                    c1 += conv1_w[p * 5 + t] * v;
                }
                float c2 = 0.f;
                #pragma unroll
                for (int t = 0; t < 9; ++t) {
                    int dd = d + t - 4;
                    float v = (dd >= 0 && dd < ND) ? rowp[dd] : 0.f;
                    c2 += conv2_w[p * 9 + t] * v;
                }
                const float a = sigmoid_f(combine_w[0] * c1 + combine_w[1] * c2 + combine_b[0]);
                if (k == 0) aa0 = a; else aa1 = a;
            }
            // per-path mean: wave p (tid in [64p,64p+64)) covers pos [128p,128p+128)
            float s = aa0 + aa1;
            s += __shfl_down(s, 32, 64); s += __shfl_down(s, 16, 64);
            s += __shfl_down(s, 8, 64);  s += __shfl_down(s, 4, 64);
            s += __shfl_down(s, 2, 64);  s += __shfl_down(s, 1, 64);
            if ((tid & 63) == 0) scross[tid >> 6] = s * (1.f / ND);
        }
        __syncthreads();
        if (tid == 0) {
            float mu = 0.f;
            #pragma unroll
            for (int pp = 0; pp < NP; ++pp) mu += scross[pp];
            mu *= (1.f / NP);
            float var = 0.f;
            #pragma unroll
            for (int pp = 0; pp < NP; ++pp) { float dl = scross[pp] - mu; var += dl * dl; }
            sml[0] = mu;
            sml[1] = rsqrtf(var * (1.f / NP) + LN_EPS);
        }
        __syncthreads();
        if (tid < NP)
            sh[tid] = (scross[tid] - sml[0]) * sml[1] * ln_g[tid] + ln_b[tid];
        __syncthreads();
        if (tid < 2 * NP) {
            float s = b1[tid];
            #pragma unroll
            for (int pp = 0; pp < NP; ++pp) s += sh[pp] * W1[pp * (2 * NP) + tid];
            sh2[tid] = gelu_f(s);
        }
        __syncthreads();
        if (tid < NP) {
            float s = b2[tid];
            #pragma unroll
            for (int j = 0; j < 2 * NP; ++j) s += sh2[j] * W2[j * NP + tid];
            sgate[tid] = sigmoid_f(s);
        }
        __syncthreads();
        if (tid == (ch0 >> 1)) {            // this thread computed attn[ch0], attn[ch0+1]
            const float g = sgate[ch0 >> 7];
            sscale[0] = aa0 * g;
            sscale[1] = aa1 * g;
        }
        __syncthreads();

        // ---- Phase C: LDS -> scale -> nt-store ----
        {
            const float sc = sscale[r];
            v4f* orow = (v4f*)out + (size_t)(r0 + r) * (NL / 4);
            __builtin_nontemporal_store(srow[r][col]       * sc, &orow[col]);
            __builtin_nontemporal_store(srow[r][col + 256] * sc, &orow[col + 256]);
            __builtin_nontemporal_store(srow[r][col + 512] * sc, &orow[col + 512]);
            __builtin_nontemporal_store(srow[r][col + 768] * sc, &orow[col + 768]);
        }
        __syncthreads();                    // LDS safe before next chunk reuses it
    }
}

// ================= Fallback path (R4 kernels, 133 us) =================
__global__ __launch_bounds__(256) void pool_kernel(const float* __restrict__ x,
                                                   float* __restrict__ y) {
    const int wid  = threadIdx.x >> 6;
    const int lane = threadIdx.x & 63;
    const int row  = blockIdx.x * 4 + wid;
    const v4f* xr = (const v4f*)(x + (size_t)row * NL);
    float s = 0.f;
    #pragma unroll
    for (int i = 0; i < 16; ++i) {
        v4f v = xr[lane + i * 64];
        s += v.x + v.y + v.z + v.w;
    }
    #pragma unroll
    for (int off = 32; off; off >>= 1) s += __shfl_down(s, off, 64);
    if (lane == 0) y[row] = s * (1.f / NL);
}

__global__ __launch_bounds__(1024) void attn_kernel(
    const float* __restrict__ y,
    const float* __restrict__ conv1_w, const float* __restrict__ conv2_w,
    const float* __restrict__ combine_w, const float* __restrict__ combine_b,
    const float* __restrict__ ln_g, const float* __restrict__ ln_b,
    const float* __restrict__ W1, const float* __restrict__ b1,
    const float* __restrict__ W2, const float* __restrict__ b2,
    float* __restrict__ scale)
{
    const int b = blockIdx.x;
    const int tid = threadIdx.x;
    const int p = tid >> 7;
    const int d = tid & 127;

    __shared__ float sy[NC];
    __shared__ float sattn[NC];
    __shared__ float sred[16];
    __shared__ float scross[NP];
    __shared__ float sh[NP];
    __shared__ float sh2[2 * NP];
    __shared__ float sgate[NP];
    __shared__ float sml[2];

    sy[tid] = y[b * NC + tid];
    __syncthreads();

    const float* rowp = sy + p * ND;
    float c1 = 0.f;
    #pragma unroll
    for (int t = 0; t < 5; ++t) {
        int dd = d + t - 2;
        float v = (dd >= 0 && dd < ND) ? rowp[dd] : 0.f;
        c1 += conv1_w[p * 5 + t] * v;
    }
    float c2 = 0.f;
    #pragma unroll
    for (int t = 0; t < 9; ++t) {
        int dd = d + t - 4;
        float v = (dd >= 0 && dd < ND) ? rowp[dd] : 0.f;
        c2 += conv2_w[p * 9 + t] * v;
    }
    const float a = sigmoid_f(combine_w[0] * c1 + combine_w[1] * c2 + combine_b[0]);
    sattn[tid] = a;

    float rr = a;
    #pragma unroll
    for (int off = 32; off; off >>= 1) rr += __shfl_down(rr, off, 64);
    const int lane = tid & 63, wid = tid >> 6;
    if (lane == 0) sred[wid] = rr;
    __syncthreads();

    if (tid == 0) {
        float mu = 0.f, var = 0.f;
        #pragma unroll
        for (int pp = 0; pp < NP; ++pp) {
            scross[pp] = (sred[2 * pp] + sred[2 * pp + 1]) * (1.f / ND);
            mu += scross[pp];
        }
        mu *= (1.f / NP);
        #pragma unroll
        for (int pp = 0; pp < NP; ++pp) { float dl = scross[pp] - mu; var += dl * dl; }
        sml[0] = mu;
        sml[1] = rsqrtf(var * (1.f / NP) + LN_EPS);
    }
    __syncthreads();
    if (tid < NP)
        sh[tid] = (scross[tid] - sml[0]) * sml[1] * ln_g[tid] + ln_b[tid];
    __syncthreads();
    if (tid < 2 * NP) {
        float s = b1[tid];
        #pragma unroll
        for (int pp = 0; pp < NP; ++pp) s += sh[pp] * W1[pp * (2 * NP) + tid];
        sh2[tid] = gelu_f(s);
    }
    __syncthreads();
    if (tid < NP) {
        float s = b2[tid];
        #pragma unroll
        for (int j = 0; j < 2 * NP; ++j) s += sh2[j] * W2[j * NP + tid];
        sgate[tid] = sigmoid_f(s);
    }
    __syncthreads();

    scale[b * NC + tid] = sattn[tid] * sgate[p];
}

__global__ __launch_bounds__(256) void scale_kernel(const float* __restrict__ x,
                                                    const float* __restrict__ scale,
                                                    float* __restrict__ out) {
    const v4f* xv = (const v4f*)x;
    v4f* ov = (v4f*)out;
    const size_t n = (size_t)NB * NC * (NL / 4);
    const size_t stride = (size_t)gridDim.x * blockDim.x;
    for (size_t i = (size_t)blockIdx.x * blockDim.x + threadIdx.x; i < n; i += stride) {
        const float s = scale[i >> 10];
        v4f v = xv[i];
        v *= s;
        __builtin_nontemporal_store(v, &ov[i]);
    }
}

extern "C" void kernel_launch(void* const* d_in, const int* in_sizes, int n_in,
                              void* d_out, int out_size, void* d_ws, size_t ws_size,
                              hipStream_t stream) {
    const float* x         = (const float*)d_in[0];
    const float* conv1_w   = (const float*)d_in[1];
    const float* conv2_w   = (const float*)d_in[2];
    const float* combine_w = (const float*)d_in[3];
    const float* combine_b = (const float*)d_in[4];
    const float* ln_g      = (const float*)d_in[5];
    const float* ln_b      = (const float*)d_in[6];
    const float* W1        = (const float*)d_in[7];
    const float* b1        = (const float*)d_in[8];
    const float* W2        = (const float*)d_in[9];
    const float* b2        = (const float*)d_in[10];
    float* out = (float*)d_out;

    float* y        = (float*)d_ws;                    // [0,64KB): pooled means
    float* scale    = y + NB * NC;                     // [64KB,128KB): fallback only
    unsigned* garr  = (unsigned*)(void*)scale;         // coop: overlaps scale region
    unsigned* grel  = garr + GRPS;
    unsigned* root  = grel + GRPS;

    // zero barrier counters each launch (graph-capturable, deterministic)
    hipMemsetAsync((void*)garr, 0, (2 * GRPS + 16) * sizeof(unsigned), stream);

    int nb = 0;
    hipOccupancyMaxActiveBlocksPerMultiprocessor(&nb, fused_kernel, NT, 0);
    if (nb >= 4) {
        void* args[] = { (void*)&x, (void*)&y, (void*)&garr, (void*)&grel, (void*)&root,
                         (void*)&conv1_w, (void*)&conv2_w,
                         (void*)&combine_w, (void*)&combine_b,
                         (void*)&ln_g, (void*)&ln_b,
                         (void*)&W1, (void*)&b1, (void*)&W2, (void*)&b2,
                         (void*)&out };
        hipLaunchCooperativeKernel((const void*)fused_kernel, dim3(NBLK), dim3(NT),
                                   args, 0, stream);
    } else {
        pool_kernel<<<NB * NC / 4, 256, 0, stream>>>(x, y);
        attn_kernel<<<NB, 1024, 0, stream>>>(y, conv1_w, conv2_w, combine_w, combine_b,
                                             ln_g, ln_b, W1, b1, W2, b2, scale);
        scale_kernel<<<2048, 256, 0, stream>>>(x, scale, out);
    }
}